// Round 7
// baseline (409.825 us; speedup 1.0000x reference)
//
#include <hip/hip_runtime.h>
#include <math.h>

#define NN 4096
#define FF 128
#define HH 4
#define HIDD 64
#define OUTD 16
#define MASKW (NN / 32)
#define ALPHA 0.2f

typedef __attribute__((ext_vector_type(8))) short short8;
typedef __attribute__((ext_vector_type(4))) float f32x4;

__device__ __forceinline__ ushort f2bf(float f) {  // RNE f32->bf16 (finite, no NaN)
    unsigned u = __float_as_uint(f);
    return (ushort)((u + 0x7fffu + ((u >> 16) & 1u)) >> 16);
}
__device__ __forceinline__ float bf2f(ushort u) {
    return __uint_as_float((unsigned)u << 16);
}

// ---------------- pack adjacency into bitmask (2 MB) ----------------
__global__ void pack_mask_kernel(const int* __restrict__ adj, unsigned int* __restrict__ mb) {
    int t = blockIdx.x * 256 + threadIdx.x;
    int v = adj[t] > 0;
    unsigned long long bal = __ballot(v);
    if ((threadIdx.x & 63) == 0) {
        int w = t >> 5;
        mb[w] = (unsigned int)(bal & 0xffffffffULL);
        mb[w + 1] = (unsigned int)(bal >> 32);
    }
}

// ---------------- cvt x -> bf16 ----------------
__global__ void cvt_kernel(const float* __restrict__ x, ushort* __restrict__ xb) {
    int e = (blockIdx.x * 256 + threadIdx.x) * 4;
    f32x4 v = *(const f32x4*)&x[e];
    unsigned lo = (unsigned)f2bf(v[0]) | ((unsigned)f2bf(v[1]) << 16);
    unsigned hi = (unsigned)f2bf(v[2]) | ((unsigned)f2bf(v[3]) << 16);
    uint2 p; p.x = lo; p.y = hi;
    *(uint2*)&xb[e] = p;
}

// ---------------- weight transpose+cast: W[hd][k][n] fp32 -> WT[hd][n][k] bf16 ----------------
__global__ void wtprep_kernel(const float* __restrict__ W_in, const float* __restrict__ W_hid,
                              const float* __restrict__ W_out,
                              ushort* __restrict__ wt1, ushort* __restrict__ wt2,
                              ushort* __restrict__ wt3) {
    int idx = blockIdx.x * 256 + threadIdx.x;
    if (idx < 65536) {  // L1: H=4, K=128, N=128
        int k = idx & 127, n = (idx >> 7) & 127, hd = idx >> 14;
        wt1[idx] = f2bf(W_in[((size_t)hd * 128 + k) * 128 + n]);
    } else if (idx < 65536 + 131072) {  // L2: H=4, K=512, N=64
        int j = idx - 65536;
        int k = j & 511, n = (j >> 9) & 63, hd = j >> 15;
        wt2[j] = f2bf(W_hid[((size_t)hd * 512 + k) * 64 + n]);
    } else if (idx < 65536 + 131072 + 4096) {  // L3: K=256, N=16
        int j = idx - 196608;
        int k = j & 255, n = j >> 8;
        wt3[j] = f2bf(W_out[(size_t)k * 16 + n]);
    }
}

// ---------------- v = W . a per head (fp32): v[(s*H+hd)*K + f] ----------------
__global__ void vprep_kernel(const float* __restrict__ W_in, const float* __restrict__ a_in,
                             const float* __restrict__ W_hid, const float* __restrict__ a_hid,
                             const float* __restrict__ W_out, const float* __restrict__ a_out,
                             float* __restrict__ vbuf) {
    int idx = blockIdx.x * 256 + threadIdx.x;
    const float* Wr; const float* ar; int D; float* dst;
    if (idx < 1024) {
        int f = idx & 127, hd = (idx >> 7) & 3, s = idx >> 9;
        Wr = W_in + ((size_t)hd * 128 + f) * 128;
        ar = a_in + hd * 256 + s * 128;
        D = 128; dst = &vbuf[idx];
    } else if (idx < 1024 + 4096) {
        int j = idx - 1024;
        int f = j & 511, hd = (j >> 9) & 3, s = j >> 11;
        Wr = W_hid + ((size_t)hd * 512 + f) * 64;
        ar = a_hid + hd * 128 + s * 64;
        D = 64; dst = &vbuf[1024 + j];
    } else if (idx < 1024 + 4096 + 512) {
        int j = idx - 5120;
        int f = j & 255, s = j >> 8;
        Wr = W_out + (size_t)f * 16;
        ar = a_out + s * 16;
        D = 16; dst = &vbuf[5120 + j];
    } else return;
    float s = 0.f;
    for (int d = 0; d < D; d++) s += Wr[d] * ar[d];
    *dst = s;
}

// ---------------- scores: f1/f2[hd][i] = A[i,:] . v{1,2}[hd,:] ----------------
template <typename T, int K, int H>
__global__ __launch_bounds__(256) void score_kernel(const T* __restrict__ A,
                                                    const float* __restrict__ v,
                                                    float* __restrict__ f1,
                                                    float* __restrict__ f2) {
    int wv = blockIdx.x * 4 + (threadIdx.x >> 6);
    int lane = threadIdx.x & 63;
    int hd = wv >> 12;
    int i = wv & (NN - 1);
    const T* ar = A + (size_t)i * K;
    const float* v1r = v + (size_t)hd * K;
    const float* v2r = v + (size_t)(H + hd) * K;
    float s1 = 0.f, s2 = 0.f;
    for (int f = lane; f < K; f += 64) {
        float av;
        if constexpr (sizeof(T) == 2) av = bf2f(((const ushort*)ar)[f]);
        else av = ((const float*)ar)[f];
        s1 += av * v1r[f];
        s2 += av * v2r[f];
    }
#pragma unroll
    for (int o = 32; o > 0; o >>= 1) {
        s1 += __shfl_down(s1, o);
        s2 += __shfl_down(s2, o);
    }
    if (lane == 0) { f1[wv] = s1; f2[wv] = s2; }
}

// ---------------- per-head global max of f2 ----------------
__global__ void gmax_kernel(const float* __restrict__ f2, float* __restrict__ gmax) {
    int hd = blockIdx.x;
    const float* p = f2 + (size_t)hd * NN;
    float m = -1e30f;
    for (int i = threadIdx.x; i < NN; i += 256) m = fmaxf(m, p[i]);
    __shared__ float sm[4];
#pragma unroll
    for (int off = 32; off > 0; off >>= 1) m = fmaxf(m, __shfl_down(m, off));
    if ((threadIdx.x & 63) == 0) sm[threadIdx.x >> 6] = m;
    __syncthreads();
    if (threadIdx.x == 0) gmax[hd] = fmaxf(fmaxf(sm[0], sm[1]), fmaxf(sm[2], sm[3]));
}

// ---------------- MFMA projection: hT[hd][n][i] = sum_k A[i][k] * WT[hd][n][k] ----------------
template <int K, int N, int CFG>
__global__ __launch_bounds__(256) void proj_mfma_kernel(const ushort* __restrict__ A,
                                                        const ushort* __restrict__ WT,
                                                        ushort* __restrict__ hT) {
    constexpr int NT = (CFG == 0) ? (N / 64) : (N / 16);
    __shared__ ushort ts[4][NT * 16][20];
    const int hd = blockIdx.y;
    const int t = threadIdx.x;
    const int w = t >> 6, lane = t & 63, ln = lane & 15, g = lane >> 4, g8 = g * 8;
    const int i0 = (CFG == 0) ? blockIdx.x * 16 : blockIdx.x * 64 + w * 16;
    const int n0 = (CFG == 0) ? w * (N / 4) : 0;
    const ushort* WTh = WT + (size_t)hd * N * K;
    ushort* hTh = hT + (size_t)hd * N * NN;
    f32x4 acc[NT];
#pragma unroll
    for (int n = 0; n < NT; n++) acc[n] = (f32x4)(0.f);
    const ushort* arow = A + (size_t)(i0 + ln) * K + g8;
#pragma unroll
    for (int k0 = 0; k0 < K; k0 += 32) {
        short8 aF = *(const short8*)&arow[k0];
#pragma unroll
        for (int n = 0; n < NT; n++) {
            short8 bF = *(const short8*)&WTh[(size_t)(n0 + n * 16 + ln) * K + k0 + g8];
            acc[n] = __builtin_amdgcn_mfma_f32_16x16x32_bf16(aF, bF, acc[n], 0, 0, 0);
        }
    }
#pragma unroll
    for (int n = 0; n < NT; n++) {
        unsigned lo = (unsigned)f2bf(acc[n][0]) | ((unsigned)f2bf(acc[n][1]) << 16);
        unsigned hi = (unsigned)f2bf(acc[n][2]) | ((unsigned)f2bf(acc[n][3]) << 16);
        uint2 p; p.x = lo; p.y = hi;
        *(uint2*)&ts[w][n * 16 + ln][g * 4] = p;
    }
#pragma unroll
    for (int n = 0; n < NT; n++) {
        int d = lane >> 2, ip = lane & 3;
        uint2 rv = *(uint2*)&ts[w][n * 16 + d][ip * 4];
        *(uint2*)&hTh[(size_t)(n0 + n * 16 + d) * NN + i0 + ip * 4] = rv;
    }
}

// ---------------- XCD-clustered j-split MFMA aggregation: fp32 partials ----------------
// 1D grid of 64*JS*H blocks. xcd = bid&7 owns consecutive combos (same hd) -> L2 locality.
// LDS is fragment-ordered: chunk ch (16B) at offset ch*16B; zero bank conflicts on
// both staging write (lane->lane*16B) and B-frag read (lane->lane*16B).
// jt=64 (2 k-steps per stage). pacc stored frag-native, 256B/wave coalesced.
template <int D>
__global__ __launch_bounds__(256) void agg4_kernel(const ushort* __restrict__ hT,
                                                   const float* __restrict__ f1,
                                                   const float* __restrict__ f2,
                                                   const float* __restrict__ gmax,
                                                   const unsigned int* __restrict__ mb,
                                                   float* __restrict__ pacc,
                                                   float* __restrict__ plsum,
                                                   int lgJS) {
    constexpr int NT = D / 16;          // MFMA col-tiles
    constexpr int CHS = NT * 64;        // 16B chunks per k-step
    constexpr int NC = NT / 2;          // chunks per thread (2 k-steps, 256 thr)
    __shared__ ushort hs[2 * CHS * 8];  // [kstep][tile][lane] * 8 ushorts
    const int JS = 1 << lgJS;
    const int jlen = NN >> lgJS;
    const int combos = JS * HH;
    const int bid = blockIdx.x;
    int ibk, combo;
    if (combos >= 8) {
        int xcd = bid & 7;
        int sid = bid >> 3;
        combo = xcd * (combos >> 3) + (sid >> 6);
        ibk = sid & 63;
    } else {
        ibk = bid & 63;
        combo = bid >> 6;
    }
    const int js = combo & (JS - 1);
    const int hd = combo >> lgJS;
    const int jb = js * jlen, je = jb + jlen;

    const int t = threadIdx.x;
    const int w = t >> 6;
    const int lane = t & 63;
    const int ln = lane & 15;
    const int g = lane >> 4;
    const int g8 = g * 8;
    const int i0 = ibk * 64 + w * 16;
    const ushort* hTh = hT + (size_t)hd * D * NN;

    const float f1v = f1[hd * NN + i0 + ln];
    const float gm = gmax[hd];
    float mi = f1v + gm;
    mi = fmaxf(mi, ALPHA * mi);
    const float L2E = 1.442695040888963f;
    const float cexp = -mi * L2E;

    f32x4 acc[NT];
#pragma unroll
    for (int n = 0; n < NT; n++) acc[n] = (f32x4)(0.f);
    float lsum = 0.f;
    const float* f2h = f2 + hd * NN;
    const unsigned* mrow = mb + (size_t)(i0 + ln) * MASKW;

    // staging decode: chunk ch -> kstep s, tile n, lane l; source row n*16+(l&15),
    // col s*32 + (l>>4)*8; LDS offset ch*8 ushorts.
    int srow[NC], scol[NC], soff[NC];
#pragma unroll
    for (int c = 0; c < NC; c++) {
        int ch = t + c * 256;
        int s = ch / CHS;
        int inner = ch - s * CHS;
        int n = inner >> 6;
        int l = inner & 63;
        srow[c] = n * 16 + (l & 15);
        scol[c] = s * 32 + (l >> 4) * 8;
        soff[c] = ch * 8;
    }
    uint4 st[NC];
#pragma unroll
    for (int c = 0; c < NC; c++)
        st[c] = *(const uint4*)&hTh[(size_t)srow[c] * NN + jb + scol[c]];

    for (int j0 = jb; j0 < je; j0 += 64) {
        __syncthreads();
#pragma unroll
        for (int c = 0; c < NC; c++) *(uint4*)&hs[soff[c]] = st[c];
        __syncthreads();
        const bool more = (j0 + 64) < je;
        if (more) {
#pragma unroll
            for (int c = 0; c < NC; c++)
                st[c] = *(const uint4*)&hTh[(size_t)srow[c] * NN + j0 + 64 + scol[c]];
        }
        uint2 mw2 = *(const uint2*)&mrow[j0 >> 5];
#pragma unroll
        for (int s = 0; s < 2; s++) {
            unsigned bits = ((s ? mw2.y : mw2.x) >> g8) & 0xffu;
            f32x4 cA = *(const f32x4*)&f2h[j0 + s * 32 + g8];
            f32x4 cB = *(const f32x4*)&f2h[j0 + s * 32 + g8 + 4];
            unsigned au[4];
#pragma unroll
            for (int tp = 0; tp < 4; tp++) {
                unsigned pu[2];
#pragma unroll
                for (int q = 0; q < 2; q++) {
                    int tt = tp * 2 + q;
                    float f2t = (tt < 4) ? cA[tt] : cB[tt - 4];
                    float e = f1v + f2t;
                    e = fmaxf(e, ALPHA * e);
                    float p = ((bits >> tt) & 1u) ? __builtin_amdgcn_exp2f(e * L2E + cexp) : 0.f;
                    pu[q] = __float_as_uint(p) & 0xffff0000u;
                    lsum += __uint_as_float(pu[q]);
                }
                au[tp] = (pu[0] >> 16) | pu[1];
            }
            union { unsigned u[4]; short8 v; } aF;
#pragma unroll
            for (int q = 0; q < 4; q++) aF.u[q] = au[q];
#pragma unroll
            for (int n = 0; n < NT; n++) {
                short8 bF = *(const short8*)&hs[((s * NT + n) * 64 + lane) * 8];
                acc[n] = __builtin_amdgcn_mfma_f32_16x16x32_bf16(aF.v, bF, acc[n], 0, 0, 0);
            }
        }
    }
    lsum += __shfl_xor(lsum, 16);
    lsum += __shfl_xor(lsum, 32);
    if (g == 0) plsum[(size_t)combo * NN + i0 + ln] = lsum;
    // frag-native pacc: [combo][i-group of 16][tile n][row-in-16][ln] -> 256B/wave stores
    float* pb = pacc + ((size_t)combo * NN + i0) * D;
#pragma unroll
    for (int n = 0; n < NT; n++) {
#pragma unroll
        for (int r = 0; r < 4; r++) {
            pb[n * 256 + (g * 4 + r) * 16 + ln] = acc[n][r];
        }
    }
}

// ---------------- combine partials (frag-native pacc): normalize + epilogue -> bf16 ----------------
template <int D, int EPI>
__global__ __launch_bounds__(256) void combine_kernel(const float* __restrict__ pacc,
                                                      const float* __restrict__ plsum,
                                                      const float* __restrict__ xres,
                                                      ushort* __restrict__ out,
                                                      int ncols, int JS) {
    const int hd = blockIdx.y;
    const int e = (blockIdx.x * 256 + threadIdx.x) * 4;
    const int row = e / D;
    const int col = e % D;
    const size_t fidx = ((size_t)(row & ~15)) * D + (col >> 4) * 256 + (row & 15) * 16 + (col & 15);
    f32x4 s = (f32x4)(0.f);
    float l = 0.f;
    for (int js = 0; js < JS; js++) {
        const size_t cix = (size_t)(hd * JS + js) * NN;
        s += *(const f32x4*)&pacc[cix * D + fidx];
        l += plsum[cix + row];
    }
    const float inv = 1.f / l;
    f32x4 xv;
    if (EPI == 1) xv = *(const f32x4*)&xres[(size_t)row * D + col];
    float o[4];
#pragma unroll
    for (int k = 0; k < 4; k++) {
        float v = s[k] * inv;
        if (EPI == 1) v += xv[k];
        if (EPI >= 1) v = v > 0.f ? v : (__expf(v) - 1.f);
        o[k] = v;
    }
    unsigned lo = (unsigned)f2bf(o[0]) | ((unsigned)f2bf(o[1]) << 16);
    unsigned hi = (unsigned)f2bf(o[2]) | ((unsigned)f2bf(o[3]) << 16);
    uint2 p; p.x = lo; p.y = hi;
    *(uint2*)&out[(size_t)row * ncols + hd * D + col] = p;
}

// ---------------- fallback: staged multi-wave MFMA aggregation (no j-split) ----------------
template <int D, int EPI>
__global__ __launch_bounds__(256) void agg2_kernel(const ushort* __restrict__ hT,
                                                   const float* __restrict__ f1,
                                                   const float* __restrict__ f2,
                                                   const float* __restrict__ gmax,
                                                   const unsigned int* __restrict__ mb,
                                                   const float* __restrict__ xres,
                                                   ushort* __restrict__ out, int ncols) {
    constexpr int NT = D / 16;
    constexpr int NC = D / 64;
    __shared__ ushort hs[D][40];
    const int hd = blockIdx.z;
    const int t = threadIdx.x;
    const int w = t >> 6;
    const int lane = t & 63;
    const int ln = lane & 15;
    const int g = lane >> 4;
    const int g8 = g * 8;
    const int i0 = blockIdx.x * 64 + w * 16;
    const ushort* hTh = hT + (size_t)hd * D * NN;
    const float f1v = f1[hd * NN + i0 + ln];
    const float gm = gmax[hd];
    float mi = f1v + gm;
    mi = fmaxf(mi, ALPHA * mi);
    const float L2E = 1.442695040888963f;
    const float cexp = -mi * L2E;
    f32x4 acc[NT];
#pragma unroll
    for (int n = 0; n < NT; n++) acc[n] = (f32x4)(0.f);
    float lsum = 0.f;
    const float* f2h = f2 + hd * NN;
    const unsigned* mrow = mb + (size_t)(i0 + ln) * MASKW;
    int srow[NC], scol[NC];
#pragma unroll
    for (int c = 0; c < NC; c++) {
        int ch = t + c * 256;
        srow[c] = ch >> 2;
        scol[c] = (ch & 3) * 8;
    }
    uint4 st[NC];
#pragma unroll
    for (int c = 0; c < NC; c++)
        st[c] = *(const uint4*)&hTh[(size_t)srow[c] * NN + scol[c]];
    unsigned mw = mrow[0];
    f32x4 fA = *(const f32x4*)&f2h[g8];
    f32x4 fB = *(const f32x4*)&f2h[g8 + 4];
    for (int j0 = 0; j0 < NN; j0 += 32) {
        __syncthreads();
#pragma unroll
        for (int c = 0; c < NC; c++) *(uint4*)&hs[srow[c]][scol[c]] = st[c];
        __syncthreads();
        const bool more = (j0 + 32) < NN;
        if (more) {
#pragma unroll
            for (int c = 0; c < NC; c++)
                st[c] = *(const uint4*)&hTh[(size_t)srow[c] * NN + j0 + 32 + scol[c]];
        }
        unsigned bits = (mw >> g8) & 0xffu;
        f32x4 cA = fA, cB = fB;
        if (more) {
            mw = mrow[(j0 + 32) >> 5];
            fA = *(const f32x4*)&f2h[j0 + 32 + g8];
            fB = *(const f32x4*)&f2h[j0 + 32 + g8 + 4];
        }
        unsigned au[4];
#pragma unroll
        for (int tp = 0; tp < 4; tp++) {
            unsigned pu[2];
#pragma unroll
            for (int q = 0; q < 2; q++) {
                int tt = tp * 2 + q;
                float f2t = (tt < 4) ? cA[tt] : cB[tt - 4];
                float e = f1v + f2t;
                e = fmaxf(e, ALPHA * e);
                float p = ((bits >> tt) & 1u) ? __builtin_amdgcn_exp2f(e * L2E + cexp) : 0.f;
                pu[q] = __float_as_uint(p) & 0xffff0000u;
                lsum += __uint_as_float(pu[q]);
            }
            au[tp] = (pu[0] >> 16) | pu[1];
        }
        union { unsigned u[4]; short8 s; } aF;
#pragma unroll
        for (int q = 0; q < 4; q++) aF.u[q] = au[q];
#pragma unroll
        for (int n = 0; n < NT; n++) {
            short8 bF = *(const short8*)&hs[n * 16 + ln][g8];
            acc[n] = __builtin_amdgcn_mfma_f32_16x16x32_bf16(aF.s, bF, acc[n], 0, 0, 0);
        }
    }
    lsum += __shfl_xor(lsum, 16);
    lsum += __shfl_xor(lsum, 32);
    const float linv = 1.f / lsum;
#pragma unroll
    for (int n = 0; n < NT; n++) {
#pragma unroll
        for (int r = 0; r < 4; r++) {
            float invr = __shfl(linv, (g << 2) + r);
            float v = acc[n][r] * invr;
            int row = i0 + g * 4 + r;
            int col = n * 16 + ln;
            if (EPI == 1) v += xres[(size_t)row * D + col];
            if (EPI >= 1) v = v > 0.f ? v : (__expf(v) - 1.f);
            out[(size_t)row * ncols + hd * D + col] = f2bf(v);
        }
    }
}

// ---------------- single-wave MFMA aggregation with in-block j-split (L3, D=16) ----------------
template <int D, int EPI, int NW>
__global__ __launch_bounds__(NW * 64) void agg_mfma_kernel(const ushort* __restrict__ hT,
                                                           const float* __restrict__ f1,
                                                           const float* __restrict__ f2,
                                                           const float* __restrict__ gmax,
                                                           const unsigned int* __restrict__ mb,
                                                           const float* __restrict__ xres,
                                                           float* __restrict__ out, int ncols) {
    constexpr int NT = D / 16;
    static_assert(NW == 1 || NT == 1, "j-split only for single-tile D");
    const int hd = blockIdx.z;
    const int i0 = blockIdx.x * 16;
    const int w = threadIdx.x >> 6;
    const int lane = threadIdx.x & 63;
    const int ln = lane & 15;
    const int g = lane >> 4;
    const int g8 = g * 8;
    const ushort* hTh = hT + (size_t)hd * D * NN;
    const float f1v = f1[hd * NN + i0 + ln];
    const float gm = gmax[hd];
    float mi = f1v + gm;
    mi = fmaxf(mi, ALPHA * mi);
    f32x4 acc[NT];
#pragma unroll
    for (int n = 0; n < NT; n++) acc[n] = (f32x4)(0.f);
    float lsum = 0.f;
    const float* f2h = f2 + hd * NN;
    const unsigned* mrow = mb + (size_t)(i0 + ln) * MASKW;
    const int jbeg = w * (NN / NW), jend = jbeg + NN / NW;

    for (int j0 = jbeg; j0 < jend; j0 += 32) {
        unsigned bits = (mrow[j0 >> 5] >> g8) & 0xffu;
        f32x4 fA = *(const f32x4*)&f2h[j0 + g8];
        f32x4 fB = *(const f32x4*)&f2h[j0 + g8 + 4];
        short8 aF;
#pragma unroll
        for (int t = 0; t < 8; t++) {
            float f2t = (t < 4) ? fA[t] : fB[t - 4];
            float e = f1v + f2t;
            e = fmaxf(e, ALPHA * e);
            float p = ((bits >> t) & 1u) ? __expf(e - mi) : 0.f;
            ushort pb = f2bf(p);
            aF[t] = (short)pb;
            lsum += __uint_as_float((unsigned)pb << 16);
        }
#pragma unroll
        for (int n = 0; n < NT; n++) {
            short8 bF = *(const short8*)&hTh[(size_t)(n * 16 + ln) * NN + j0 + g8];
            acc[n] = __builtin_amdgcn_mfma_f32_16x16x32_bf16(aF, bF, acc[n], 0, 0, 0);
        }
    }
    lsum += __shfl_xor(lsum, 16);
    lsum += __shfl_xor(lsum, 32);

    float accF[NT][4];
    float ltot;
    __shared__ float accL[NW][16][17];
    __shared__ float lsL[NW][16];
    if constexpr (NW == 1) {
#pragma unroll
        for (int n = 0; n < NT; n++)
#pragma unroll
            for (int r = 0; r < 4; r++) accF[n][r] = acc[n][r];
        ltot = lsum;
    } else {
#pragma unroll
        for (int r = 0; r < 4; r++) accL[w][g * 4 + r][ln] = acc[0][r];
        if (lane < 16) lsL[w][lane] = lsum;
        __syncthreads();
        if (w != 0) return;
#pragma unroll
        for (int r = 0; r < 4; r++) {
            float s = 0.f;
            for (int ww = 0; ww < NW; ww++) s += accL[ww][g * 4 + r][ln];
            accF[0][r] = s;
        }
        float s = 0.f;
        for (int ww = 0; ww < NW; ww++) s += lsL[ww][ln];
        ltot = s;
    }
    const float linv = 1.f / ltot;
#pragma unroll
    for (int n = 0; n < NT; n++) {
#pragma unroll
        for (int r = 0; r < 4; r++) {
            float invr = __shfl(linv, (g << 2) + r);
            float v = accF[n][r] * invr;
            int row = i0 + g * 4 + r;
            int col = n * 16 + ln;
            if (EPI == 1) v += xres[(size_t)row * D + col];
            if (EPI >= 1) v = v > 0.f ? v : (__expf(v) - 1.f);
            out[(size_t)row * ncols + hd * D + col] = v;
        }
    }
}

// ---------------- final: log_softmax(elu(h3)) over 16 cols ----------------
__global__ void final_kernel(const float* __restrict__ h3, float* __restrict__ out) {
    int i = blockIdx.x * 256 + threadIdx.x;
    if (i >= NN) return;
    float v[OUTD];
    float mx = -1e30f;
#pragma unroll
    for (int k = 0; k < OUTD; k++) {
        float e = h3[(size_t)i * OUTD + k];
        e = e > 0.f ? e : (__expf(e) - 1.f);
        v[k] = e;
        mx = fmaxf(mx, e);
    }
    float s = 0.f;
#pragma unroll
    for (int k = 0; k < OUTD; k++) s += __expf(v[k] - mx);
    float ls = logf(s);
#pragma unroll
    for (int k = 0; k < OUTD; k++) out[(size_t)i * OUTD + k] = v[k] - mx - ls;
}

extern "C" void kernel_launch(void* const* d_in, const int* in_sizes, int n_in,
                              void* d_out, int out_size, void* d_ws, size_t ws_size,
                              hipStream_t stream) {
    const float* x = (const float*)d_in[0];
    const int* adj = (const int*)d_in[1];
    const float* W_in = (const float*)d_in[2];
    const float* a_in = (const float*)d_in[3];
    const float* W_hid = (const float*)d_in[4];
    const float* a_hid = (const float*)d_in[5];
    const float* W_out = (const float*)d_in[6];
    const float* a_out = (const float*)d_in[7];
    float* out = (float*)d_out;

    char* w = (char*)d_ws;
    unsigned int* mb = (unsigned int*)w;  w += (size_t)NN * MASKW * 4;            // 2 MB
    ushort* hT = (ushort*)w;              w += (size_t)HH * NN * FF * 2;          // 4 MB
    ushort* xb16 = (ushort*)w;            w += (size_t)NN * FF * 2;               // 1 MB
    ushort* cat1b = (ushort*)w;           w += (size_t)NN * (HH * FF) * 2;        // 4 MB
    ushort* cat2b = (ushort*)w;           w += (size_t)NN * (HH * HIDD) * 2;      // 2 MB
    ushort* wt1 = (ushort*)w;             w += 65536 * 2;
    ushort* wt2 = (ushort*)w;             w += 131072 * 2;
    ushort* wt3 = (ushort*)w;             w += 4096 * 2;
    float* vbuf = (float*)w;              w += 5632 * 4;
    float* f1 = (float*)w;                w += (size_t)HH * NN * 4;
    float* f2 = (float*)w;                w += (size_t)HH * NN * 4;
    float* gm = (float*)w;                w += 256;
    float* h3 = (float*)w;                w += (size_t)NN * OUTD * 4;             // 256 KB
    size_t base_used = (size_t)(w - (char*)d_ws);

    // j-split factor chosen from available workspace (constant across calls)
    int lgJS = -1;
    float* pacc = (float*)w;
    float* plsum = nullptr;
    {
        size_t per_js = (size_t)HH * NN * FF * 4;   // L1 pacc bytes per js (8.4 MB)
        size_t ls_per_js = (size_t)HH * NN * 4;
        for (int lg = 3; lg >= 0; lg--) {
            size_t cand = (size_t)1 << lg;
            size_t need = base_used + cand * per_js + 8 * ls_per_js + 1024;
            if (ws_size >= need) { lgJS = lg; break; }
        }
        if (lgJS >= 0) plsum = (float*)((char*)pacc + ((size_t)1 << lgJS) * per_js);
    }
    const int JS = (lgJS >= 0) ? (1 << lgJS) : 0;
    const int lgJS2 = (lgJS >= 3) ? 3 : lgJS + 1;   // L2 split (cap 8)
    const int JS2 = 1 << lgJS2;

    // ---- prep ----
    hipLaunchKernelGGL(pack_mask_kernel, dim3(NN * NN / 256), dim3(256), 0, stream, adj, mb);
    hipLaunchKernelGGL(cvt_kernel, dim3(NN * FF / 1024), dim3(256), 0, stream, x, xb16);
    hipLaunchKernelGGL(wtprep_kernel, dim3(784), dim3(256), 0, stream,
                       W_in, W_hid, W_out, wt1, wt2, wt3);
    hipLaunchKernelGGL(vprep_kernel, dim3(22), dim3(256), 0, stream,
                       W_in, a_in, W_hid, a_hid, W_out, a_out, vbuf);

    // ---- layer 1: K=128, D=128, 4 heads, residual+elu -> cat1b[N,512] bf16
    hipLaunchKernelGGL((proj_mfma_kernel<FF, FF, 0>), dim3(NN / 16, HH), dim3(256), 0, stream,
                       xb16, wt1, hT);
    hipLaunchKernelGGL((score_kernel<float, FF, HH>), dim3(HH * NN / 4), dim3(256), 0, stream,
                       x, vbuf, f1, f2);
    hipLaunchKernelGGL(gmax_kernel, dim3(HH), dim3(256), 0, stream, f2, gm);
    if (JS) {
        hipLaunchKernelGGL((agg4_kernel<FF>), dim3(64 * JS * HH), dim3(256), 0, stream,
                           hT, f1, f2, gm, mb, pacc, plsum, lgJS);
        hipLaunchKernelGGL((combine_kernel<FF, 1>), dim3(NN * FF / 1024, HH), dim3(256), 0, stream,
                           pacc, plsum, x, cat1b, HH * FF, JS);
    } else {
        hipLaunchKernelGGL((agg2_kernel<FF, 1>), dim3(NN / 64, 1, HH), dim3(256), 0, stream,
                           hT, f1, f2, gm, mb, x, cat1b, HH * FF);
    }

    // ---- layer 2: K=512, D=64, 4 heads, elu -> cat2b[N,256] bf16
    hipLaunchKernelGGL((proj_mfma_kernel<HH * FF, HIDD, 0>), dim3(NN / 16, HH), dim3(256), 0, stream,
                       cat1b, wt2, hT);
    hipLaunchKernelGGL((score_kernel<ushort, HH * FF, HH>), dim3(HH * NN / 4), dim3(256), 0, stream,
                       cat1b, vbuf + 1024, f1, f2);
    hipLaunchKernelGGL(gmax_kernel, dim3(HH), dim3(256), 0, stream, f2, gm);
    if (JS) {
        hipLaunchKernelGGL((agg4_kernel<HIDD>), dim3(64 * JS2 * HH), dim3(256), 0, stream,
                           hT, f1, f2, gm, mb, pacc, plsum, lgJS2);
        hipLaunchKernelGGL((combine_kernel<HIDD, 2>), dim3(NN * HIDD / 1024, HH), dim3(256), 0, stream,
                           pacc, plsum, (const float*)nullptr, cat2b, HH * HIDD, JS2);
    } else {
        hipLaunchKernelGGL((agg2_kernel<HIDD, 2>), dim3(NN / 64, 1, HH), dim3(256), 0, stream,
                           hT, f1, f2, gm, mb, (const float*)nullptr, cat2b, HH * HIDD);
    }

    // ---- layer 3: K=256, D=16, 1 head -> h3[N,16] fp32
    hipLaunchKernelGGL((proj_mfma_kernel<HH * HIDD, OUTD, 1>), dim3(NN / 64, 1), dim3(256), 0, stream,
                       cat2b, wt3, hT);
    hipLaunchKernelGGL((score_kernel<ushort, HH * HIDD, 1>), dim3(NN / 4), dim3(256), 0, stream,
                       cat2b, vbuf + 5120, f1, f2);
    hipLaunchKernelGGL(gmax_kernel, dim3(1), dim3(256), 0, stream, f2, gm);
    hipLaunchKernelGGL((agg_mfma_kernel<OUTD, 0, 4>), dim3(NN / 16, 1, 1), dim3(256), 0, stream,
                       hT, f1, f2, gm, mb, (const float*)nullptr, h3, OUTD);

    hipLaunchKernelGGL(final_kernel, dim3(NN / 256), dim3(256), 0, stream, h3, out);
}

// Round 8
// 358.109 us; speedup vs baseline: 1.1444x; 1.1444x over previous
//
#include <hip/hip_runtime.h>
#include <math.h>

#define NN 4096
#define FF 128
#define HH 4
#define HIDD 64
#define OUTD 16
#define MASKW (NN / 32)
#define ALPHA 0.2f

typedef __attribute__((ext_vector_type(8))) short short8;
typedef __attribute__((ext_vector_type(4))) float f32x4;

__device__ __forceinline__ ushort f2bf(float f) {  // RNE f32->bf16 (finite, no NaN)
    unsigned u = __float_as_uint(f);
    return (ushort)((u + 0x7fffu + ((u >> 16) & 1u)) >> 16);
}
__device__ __forceinline__ float bf2f(ushort u) {
    return __uint_as_float((unsigned)u << 16);
}

// ---------------- pack adjacency into bitmask (2 MB) ----------------
__global__ void pack_mask_kernel(const int* __restrict__ adj, unsigned int* __restrict__ mb) {
    int t = blockIdx.x * 256 + threadIdx.x;
    int v = adj[t] > 0;
    unsigned long long bal = __ballot(v);
    if ((threadIdx.x & 63) == 0) {
        int w = t >> 5;
        mb[w] = (unsigned int)(bal & 0xffffffffULL);
        mb[w + 1] = (unsigned int)(bal >> 32);
    }
}

// ---------------- cvt x -> bf16 ----------------
__global__ void cvt_kernel(const float* __restrict__ x, ushort* __restrict__ xb) {
    int e = (blockIdx.x * 256 + threadIdx.x) * 4;
    f32x4 v = *(const f32x4*)&x[e];
    unsigned lo = (unsigned)f2bf(v[0]) | ((unsigned)f2bf(v[1]) << 16);
    unsigned hi = (unsigned)f2bf(v[2]) | ((unsigned)f2bf(v[3]) << 16);
    uint2 p; p.x = lo; p.y = hi;
    *(uint2*)&xb[e] = p;
}

// ---------------- weight transpose+cast: W[hd][k][n] fp32 -> WT[hd][n][k] bf16 ----------------
__global__ void wtprep_kernel(const float* __restrict__ W_in, const float* __restrict__ W_hid,
                              const float* __restrict__ W_out,
                              ushort* __restrict__ wt1, ushort* __restrict__ wt2,
                              ushort* __restrict__ wt3) {
    int idx = blockIdx.x * 256 + threadIdx.x;
    if (idx < 65536) {  // L1: H=4, K=128, N=128
        int k = idx & 127, n = (idx >> 7) & 127, hd = idx >> 14;
        wt1[idx] = f2bf(W_in[((size_t)hd * 128 + k) * 128 + n]);
    } else if (idx < 65536 + 131072) {  // L2: H=4, K=512, N=64
        int j = idx - 65536;
        int k = j & 511, n = (j >> 9) & 63, hd = j >> 15;
        wt2[j] = f2bf(W_hid[((size_t)hd * 512 + k) * 64 + n]);
    } else if (idx < 65536 + 131072 + 4096) {  // L3: K=256, N=16
        int j = idx - 196608;
        int k = j & 255, n = j >> 8;
        wt3[j] = f2bf(W_out[(size_t)k * 16 + n]);
    }
}

// ---------------- v = W . a per head (fp32): v[(s*H+hd)*K + f] ----------------
__global__ void vprep_kernel(const float* __restrict__ W_in, const float* __restrict__ a_in,
                             const float* __restrict__ W_hid, const float* __restrict__ a_hid,
                             const float* __restrict__ W_out, const float* __restrict__ a_out,
                             float* __restrict__ vbuf) {
    int idx = blockIdx.x * 256 + threadIdx.x;
    const float* Wr; const float* ar; int D; float* dst;
    if (idx < 1024) {
        int f = idx & 127, hd = (idx >> 7) & 3, s = idx >> 9;
        Wr = W_in + ((size_t)hd * 128 + f) * 128;
        ar = a_in + hd * 256 + s * 128;
        D = 128; dst = &vbuf[idx];
    } else if (idx < 1024 + 4096) {
        int j = idx - 1024;
        int f = j & 511, hd = (j >> 9) & 3, s = j >> 11;
        Wr = W_hid + ((size_t)hd * 512 + f) * 64;
        ar = a_hid + hd * 128 + s * 64;
        D = 64; dst = &vbuf[1024 + j];
    } else if (idx < 1024 + 4096 + 512) {
        int j = idx - 5120;
        int f = j & 255, s = j >> 8;
        Wr = W_out + (size_t)f * 16;
        ar = a_out + s * 16;
        D = 16; dst = &vbuf[5120 + j];
    } else return;
    float s = 0.f;
    for (int d = 0; d < D; d++) s += Wr[d] * ar[d];
    *dst = s;
}

// ---------------- scores: f1/f2[hd][i] = A[i,:] . v{1,2}[hd,:] ----------------
template <typename T, int K, int H>
__global__ __launch_bounds__(256) void score_kernel(const T* __restrict__ A,
                                                    const float* __restrict__ v,
                                                    float* __restrict__ f1,
                                                    float* __restrict__ f2) {
    int wv = blockIdx.x * 4 + (threadIdx.x >> 6);
    int lane = threadIdx.x & 63;
    int hd = wv >> 12;
    int i = wv & (NN - 1);
    const T* ar = A + (size_t)i * K;
    const float* v1r = v + (size_t)hd * K;
    const float* v2r = v + (size_t)(H + hd) * K;
    float s1 = 0.f, s2 = 0.f;
    for (int f = lane; f < K; f += 64) {
        float av;
        if constexpr (sizeof(T) == 2) av = bf2f(((const ushort*)ar)[f]);
        else av = ((const float*)ar)[f];
        s1 += av * v1r[f];
        s2 += av * v2r[f];
    }
#pragma unroll
    for (int o = 32; o > 0; o >>= 1) {
        s1 += __shfl_down(s1, o);
        s2 += __shfl_down(s2, o);
    }
    if (lane == 0) { f1[wv] = s1; f2[wv] = s2; }
}

// ---------------- per-head global max of f2 ----------------
__global__ void gmax_kernel(const float* __restrict__ f2, float* __restrict__ gmax) {
    int hd = blockIdx.x;
    const float* p = f2 + (size_t)hd * NN;
    float m = -1e30f;
    for (int i = threadIdx.x; i < NN; i += 256) m = fmaxf(m, p[i]);
    __shared__ float sm[4];
#pragma unroll
    for (int off = 32; off > 0; off >>= 1) m = fmaxf(m, __shfl_down(m, off));
    if ((threadIdx.x & 63) == 0) sm[threadIdx.x >> 6] = m;
    __syncthreads();
    if (threadIdx.x == 0) gmax[hd] = fmaxf(fmaxf(sm[0], sm[1]), fmaxf(sm[2], sm[3]));
}

// ---------------- MFMA projection: hT[hd][n][i] = sum_k A[i][k] * WT[hd][n][k] ----------------
template <int K, int N, int CFG>
__global__ __launch_bounds__(256) void proj_mfma_kernel(const ushort* __restrict__ A,
                                                        const ushort* __restrict__ WT,
                                                        ushort* __restrict__ hT) {
    constexpr int NT = (CFG == 0) ? (N / 64) : (N / 16);
    __shared__ ushort ts[4][NT * 16][20];
    const int hd = blockIdx.y;
    const int t = threadIdx.x;
    const int w = t >> 6, lane = t & 63, ln = lane & 15, g = lane >> 4, g8 = g * 8;
    const int i0 = (CFG == 0) ? blockIdx.x * 16 : blockIdx.x * 64 + w * 16;
    const int n0 = (CFG == 0) ? w * (N / 4) : 0;
    const ushort* WTh = WT + (size_t)hd * N * K;
    ushort* hTh = hT + (size_t)hd * N * NN;
    f32x4 acc[NT];
#pragma unroll
    for (int n = 0; n < NT; n++) acc[n] = (f32x4)(0.f);
    const ushort* arow = A + (size_t)(i0 + ln) * K + g8;
#pragma unroll
    for (int k0 = 0; k0 < K; k0 += 32) {
        short8 aF = *(const short8*)&arow[k0];
#pragma unroll
        for (int n = 0; n < NT; n++) {
            short8 bF = *(const short8*)&WTh[(size_t)(n0 + n * 16 + ln) * K + k0 + g8];
            acc[n] = __builtin_amdgcn_mfma_f32_16x16x32_bf16(aF, bF, acc[n], 0, 0, 0);
        }
    }
#pragma unroll
    for (int n = 0; n < NT; n++) {
        unsigned lo = (unsigned)f2bf(acc[n][0]) | ((unsigned)f2bf(acc[n][1]) << 16);
        unsigned hi = (unsigned)f2bf(acc[n][2]) | ((unsigned)f2bf(acc[n][3]) << 16);
        uint2 p; p.x = lo; p.y = hi;
        *(uint2*)&ts[w][n * 16 + ln][g * 4] = p;
    }
#pragma unroll
    for (int n = 0; n < NT; n++) {
        int d = lane >> 2, ip = lane & 3;
        uint2 rv = *(uint2*)&ts[w][n * 16 + d][ip * 4];
        *(uint2*)&hTh[(size_t)(n0 + n * 16 + d) * NN + i0 + ip * 4] = rv;
    }
}

// ---------------- intra-block j-split MFMA aggregation (L1/L2) ----------------
// Block = 4 waves, all on the SAME 32 i-rows (2 row-tiles/wave); wave w covers
// j in [w*N/4, (w+1)*N/4). B-frags read directly from L2-resident hT (no LDS
// staging, no loop barriers). lsum via extra MFMA vs all-ones B (sums the SAME
// bf16 p's). Epilogue: waves 1-3 dump fp32 C to LDS (stride-17 skew), wave 0
// reduces + normalizes + epilogue + writes bf16 cat. XCD-clustered decode.
template <int D, int EPI>
__global__ __launch_bounds__(256) void agg5_kernel(const ushort* __restrict__ hT,
                                                   const float* __restrict__ f1,
                                                   const float* __restrict__ f2,
                                                   const float* __restrict__ gmax,
                                                   const unsigned int* __restrict__ mb,
                                                   const float* __restrict__ xres,
                                                   ushort* __restrict__ out, int ncols) {
    constexpr int NT = D / 16;
    __shared__ float red[3][2 * NT * 272];   // 16 rows/tile, stride 17 (bank skew)
    __shared__ float redl[3][2][16];
    const int bid = blockIdx.x;
    const int xcd = bid & 7;
    const int hd = xcd >> 1;                       // 2 XCDs per head -> hT/mask L2-local
    const int ig = ((xcd & 1) << 6) + (bid >> 3);  // 0..127
    const int i0 = ig * 32;
    const int t = threadIdx.x;
    const int w = t >> 6;
    const int lane = t & 63;
    const int ln = lane & 15;
    const int g = lane >> 4;
    const int g8 = g * 8;
    const ushort* hTh = hT + (size_t)hd * D * NN;
    const float* f2h = f2 + hd * NN;
    const float gm = gmax[hd];
    const float L2E = 1.442695040888963f;
    float f1v[2], cexp[2];
#pragma unroll
    for (int it = 0; it < 2; it++) {
        float f = f1[hd * NN + i0 + it * 16 + ln];
        f1v[it] = f;
        float mi = f + gm;
        mi = fmaxf(mi, ALPHA * mi);
        cexp[it] = -mi * L2E;
    }
    f32x4 acc[2][NT];
#pragma unroll
    for (int it = 0; it < 2; it++)
#pragma unroll
        for (int n = 0; n < NT; n++) acc[it][n] = (f32x4)(0.f);
    f32x4 accl[2];
    accl[0] = (f32x4)(0.f);
    accl[1] = (f32x4)(0.f);
    short8 bONE;
#pragma unroll
    for (int q = 0; q < 8; q++) bONE[q] = (short)0x3F80;  // bf16 1.0

    const unsigned* mrow0 = mb + (size_t)(i0 + ln) * MASKW;
    const unsigned* mrow1 = mrow0 + 16 * MASKW;
    const int jb = w * (NN / 4), je = jb + NN / 4;
    unsigned m0 = mrow0[jb >> 5], m1 = mrow1[jb >> 5];
    f32x4 cA = *(const f32x4*)&f2h[jb + g8];
    f32x4 cB = *(const f32x4*)&f2h[jb + g8 + 4];

    for (int j0 = jb; j0 < je; j0 += 32) {
        short8 bf[NT];
#pragma unroll
        for (int n = 0; n < NT; n++)
            bf[n] = *(const short8*)&hTh[(size_t)(n * 16 + ln) * NN + j0 + g8];
        unsigned cm0 = m0, cm1 = m1;
        f32x4 fA = cA, fB = cB;
        if (j0 + 32 < je) {  // prefetch next step's A-inputs
            m0 = mrow0[(j0 + 32) >> 5];
            m1 = mrow1[(j0 + 32) >> 5];
            cA = *(const f32x4*)&f2h[j0 + 32 + g8];
            cB = *(const f32x4*)&f2h[j0 + 32 + g8 + 4];
        }
        unsigned bits0 = (cm0 >> g8) & 0xffu;
        unsigned bits1 = (cm1 >> g8) & 0xffu;
        union { unsigned u[4]; short8 v; } aF[2];
#pragma unroll
        for (int tp = 0; tp < 4; tp++) {
            unsigned pu[2][2];
#pragma unroll
            for (int q = 0; q < 2; q++) {
                int tt = tp * 2 + q;
                float f2t = (tt < 4) ? fA[tt] : fB[tt - 4];
#pragma unroll
                for (int it = 0; it < 2; it++) {
                    float e = f1v[it] + f2t;
                    e = fmaxf(e, ALPHA * e);
                    unsigned b = it ? bits1 : bits0;
                    float p = ((b >> tt) & 1u) ? __builtin_amdgcn_exp2f(e * L2E + cexp[it]) : 0.f;
                    pu[it][q] = __float_as_uint(p) & 0xffff0000u;  // truncate to bf16
                }
            }
            aF[0].u[tp] = (pu[0][0] >> 16) | pu[0][1];
            aF[1].u[tp] = (pu[1][0] >> 16) | pu[1][1];
        }
#pragma unroll
        for (int it = 0; it < 2; it++) {
#pragma unroll
            for (int n = 0; n < NT; n++)
                acc[it][n] = __builtin_amdgcn_mfma_f32_16x16x32_bf16(aF[it].v, bf[n], acc[it][n], 0, 0, 0);
            accl[it] = __builtin_amdgcn_mfma_f32_16x16x32_bf16(aF[it].v, bONE, accl[it], 0, 0, 0);
        }
    }
    // cross-wave reduction via LDS
    if (w != 0) {
        float* rb = red[w - 1];
#pragma unroll
        for (int it = 0; it < 2; it++) {
#pragma unroll
            for (int n = 0; n < NT; n++)
#pragma unroll
                for (int r = 0; r < 4; r++)
                    rb[(it * NT + n) * 272 + (g * 4 + r) * 17 + ln] = acc[it][n][r];
            if (ln == 0) {
#pragma unroll
                for (int r = 0; r < 4; r++) redl[w - 1][it][g * 4 + r] = accl[it][r];
            }
        }
    }
    __syncthreads();
    if (w != 0) return;
#pragma unroll
    for (int it = 0; it < 2; it++) {
        f32x4 lt = accl[it];
#pragma unroll
        for (int b = 0; b < 3; b++)
#pragma unroll
            for (int r = 0; r < 4; r++) lt[r] += redl[b][it][g * 4 + r];
        f32x4 linv;
#pragma unroll
        for (int r = 0; r < 4; r++) linv[r] = 1.f / lt[r];
#pragma unroll
        for (int n = 0; n < NT; n++) {
            f32x4 s = acc[it][n];
#pragma unroll
            for (int b = 0; b < 3; b++)
#pragma unroll
                for (int r = 0; r < 4; r++)
                    s[r] += red[b][(it * NT + n) * 272 + (g * 4 + r) * 17 + ln];
#pragma unroll
            for (int r = 0; r < 4; r++) {
                float v = s[r] * linv[r];
                int row = i0 + it * 16 + g * 4 + r;
                int col = n * 16 + ln;
                if (EPI == 1) v += xres[(size_t)row * D + col];
                if (EPI >= 1) v = v > 0.f ? v : (__expf(v) - 1.f);
                out[(size_t)row * ncols + hd * D + col] = f2bf(v);
            }
        }
    }
}

// ---------------- single-wave MFMA aggregation with in-block j-split (L3, D=16) ----------------
template <int D, int EPI, int NW>
__global__ __launch_bounds__(NW * 64) void agg_mfma_kernel(const ushort* __restrict__ hT,
                                                           const float* __restrict__ f1,
                                                           const float* __restrict__ f2,
                                                           const float* __restrict__ gmax,
                                                           const unsigned int* __restrict__ mb,
                                                           const float* __restrict__ xres,
                                                           float* __restrict__ out, int ncols) {
    constexpr int NT = D / 16;
    static_assert(NW == 1 || NT == 1, "j-split only for single-tile D");
    const int hd = blockIdx.z;
    const int i0 = blockIdx.x * 16;
    const int w = threadIdx.x >> 6;
    const int lane = threadIdx.x & 63;
    const int ln = lane & 15;
    const int g = lane >> 4;
    const int g8 = g * 8;
    const ushort* hTh = hT + (size_t)hd * D * NN;
    const float f1v = f1[hd * NN + i0 + ln];
    const float gm = gmax[hd];
    float mi = f1v + gm;
    mi = fmaxf(mi, ALPHA * mi);
    f32x4 acc[NT];
#pragma unroll
    for (int n = 0; n < NT; n++) acc[n] = (f32x4)(0.f);
    float lsum = 0.f;
    const float* f2h = f2 + hd * NN;
    const unsigned* mrow = mb + (size_t)(i0 + ln) * MASKW;
    const int jbeg = w * (NN / NW), jend = jbeg + NN / NW;

    for (int j0 = jbeg; j0 < jend; j0 += 32) {
        unsigned bits = (mrow[j0 >> 5] >> g8) & 0xffu;
        f32x4 fA = *(const f32x4*)&f2h[j0 + g8];
        f32x4 fB = *(const f32x4*)&f2h[j0 + g8 + 4];
        short8 aF;
#pragma unroll
        for (int t = 0; t < 8; t++) {
            float f2t = (t < 4) ? fA[t] : fB[t - 4];
            float e = f1v + f2t;
            e = fmaxf(e, ALPHA * e);
            float p = ((bits >> t) & 1u) ? __expf(e - mi) : 0.f;
            ushort pb = f2bf(p);
            aF[t] = (short)pb;
            lsum += __uint_as_float((unsigned)pb << 16);
        }
#pragma unroll
        for (int n = 0; n < NT; n++) {
            short8 bF = *(const short8*)&hTh[(size_t)(n * 16 + ln) * NN + j0 + g8];
            acc[n] = __builtin_amdgcn_mfma_f32_16x16x32_bf16(aF, bF, acc[n], 0, 0, 0);
        }
    }
    lsum += __shfl_xor(lsum, 16);
    lsum += __shfl_xor(lsum, 32);

    float accF[NT][4];
    float ltot;
    __shared__ float accL[NW][16][17];
    __shared__ float lsL[NW][16];
    if constexpr (NW == 1) {
#pragma unroll
        for (int n = 0; n < NT; n++)
#pragma unroll
            for (int r = 0; r < 4; r++) accF[n][r] = acc[n][r];
        ltot = lsum;
    } else {
#pragma unroll
        for (int r = 0; r < 4; r++) accL[w][g * 4 + r][ln] = acc[0][r];
        if (lane < 16) lsL[w][lane] = lsum;
        __syncthreads();
        if (w != 0) return;
#pragma unroll
        for (int r = 0; r < 4; r++) {
            float s = 0.f;
            for (int ww = 0; ww < NW; ww++) s += accL[ww][g * 4 + r][ln];
            accF[0][r] = s;
        }
        float s = 0.f;
        for (int ww = 0; ww < NW; ww++) s += lsL[ww][ln];
        ltot = s;
    }
    const float linv = 1.f / ltot;
#pragma unroll
    for (int n = 0; n < NT; n++) {
#pragma unroll
        for (int r = 0; r < 4; r++) {
            float invr = __shfl(linv, (g << 2) + r);
            float v = accF[n][r] * invr;
            int row = i0 + g * 4 + r;
            int col = n * 16 + ln;
            if (EPI == 1) v += xres[(size_t)row * D + col];
            if (EPI >= 1) v = v > 0.f ? v : (__expf(v) - 1.f);
            out[(size_t)row * ncols + hd * D + col] = v;
        }
    }
}

// ---------------- final: log_softmax(elu(h3)) over 16 cols ----------------
__global__ void final_kernel(const float* __restrict__ h3, float* __restrict__ out) {
    int i = blockIdx.x * 256 + threadIdx.x;
    if (i >= NN) return;
    float v[OUTD];
    float mx = -1e30f;
#pragma unroll
    for (int k = 0; k < OUTD; k++) {
        float e = h3[(size_t)i * OUTD + k];
        e = e > 0.f ? e : (__expf(e) - 1.f);
        v[k] = e;
        mx = fmaxf(mx, e);
    }
    float s = 0.f;
#pragma unroll
    for (int k = 0; k < OUTD; k++) s += __expf(v[k] - mx);
    float ls = logf(s);
#pragma unroll
    for (int k = 0; k < OUTD; k++) out[(size_t)i * OUTD + k] = v[k] - mx - ls;
}

extern "C" void kernel_launch(void* const* d_in, const int* in_sizes, int n_in,
                              void* d_out, int out_size, void* d_ws, size_t ws_size,
                              hipStream_t stream) {
    const float* x = (const float*)d_in[0];
    const int* adj = (const int*)d_in[1];
    const float* W_in = (const float*)d_in[2];
    const float* a_in = (const float*)d_in[3];
    const float* W_hid = (const float*)d_in[4];
    const float* a_hid = (const float*)d_in[5];
    const float* W_out = (const float*)d_in[6];
    const float* a_out = (const float*)d_in[7];
    float* out = (float*)d_out;

    char* w = (char*)d_ws;
    unsigned int* mb = (unsigned int*)w;  w += (size_t)NN * MASKW * 4;            // 2 MB
    ushort* hT = (ushort*)w;              w += (size_t)HH * NN * FF * 2;          // 4 MB
    ushort* xb16 = (ushort*)w;            w += (size_t)NN * FF * 2;               // 1 MB
    ushort* cat1b = (ushort*)w;           w += (size_t)NN * (HH * FF) * 2;        // 4 MB
    ushort* cat2b = (ushort*)w;           w += (size_t)NN * (HH * HIDD) * 2;      // 2 MB
    ushort* wt1 = (ushort*)w;             w += 65536 * 2;
    ushort* wt2 = (ushort*)w;             w += 131072 * 2;
    ushort* wt3 = (ushort*)w;             w += 4096 * 2;
    float* vbuf = (float*)w;              w += 5632 * 4;
    float* f1 = (float*)w;                w += (size_t)HH * NN * 4;
    float* f2 = (float*)w;                w += (size_t)HH * NN * 4;
    float* gm = (float*)w;                w += 256;
    float* h3 = (float*)w;                w += (size_t)NN * OUTD * 4;             // 256 KB

    // ---- prep ----
    hipLaunchKernelGGL(pack_mask_kernel, dim3(NN * NN / 256), dim3(256), 0, stream, adj, mb);
    hipLaunchKernelGGL(cvt_kernel, dim3(NN * FF / 1024), dim3(256), 0, stream, x, xb16);
    hipLaunchKernelGGL(wtprep_kernel, dim3(784), dim3(256), 0, stream,
                       W_in, W_hid, W_out, wt1, wt2, wt3);
    hipLaunchKernelGGL(vprep_kernel, dim3(22), dim3(256), 0, stream,
                       W_in, a_in, W_hid, a_hid, W_out, a_out, vbuf);

    // ---- layer 1: K=128, D=128, 4 heads, residual+elu -> cat1b[N,512] bf16
    hipLaunchKernelGGL((proj_mfma_kernel<FF, FF, 0>), dim3(NN / 16, HH), dim3(256), 0, stream,
                       xb16, wt1, hT);
    hipLaunchKernelGGL((score_kernel<float, FF, HH>), dim3(HH * NN / 4), dim3(256), 0, stream,
                       x, vbuf, f1, f2);
    hipLaunchKernelGGL(gmax_kernel, dim3(HH), dim3(256), 0, stream, f2, gm);
    hipLaunchKernelGGL((agg5_kernel<FF, 1>), dim3((NN / 32) * HH), dim3(256), 0, stream,
                       hT, f1, f2, gm, mb, x, cat1b, HH * FF);

    // ---- layer 2: K=512, D=64, 4 heads, elu -> cat2b[N,256] bf16
    hipLaunchKernelGGL((proj_mfma_kernel<HH * FF, HIDD, 0>), dim3(NN / 16, HH), dim3(256), 0, stream,
                       cat1b, wt2, hT);
    hipLaunchKernelGGL((score_kernel<ushort, HH * FF, HH>), dim3(HH * NN / 4), dim3(256), 0, stream,
                       cat1b, vbuf + 1024, f1, f2);
    hipLaunchKernelGGL(gmax_kernel, dim3(HH), dim3(256), 0, stream, f2, gm);
    hipLaunchKernelGGL((agg5_kernel<HIDD, 2>), dim3((NN / 32) * HH), dim3(256), 0, stream,
                       hT, f1, f2, gm, mb, (const float*)nullptr, cat2b, HH * HIDD);

    // ---- layer 3: K=256, D=16, 1 head -> h3[N,16] fp32
    hipLaunchKernelGGL((proj_mfma_kernel<HH * HIDD, OUTD, 1>), dim3(NN / 64, 1), dim3(256), 0, stream,
                       cat2b, wt3, hT);
    hipLaunchKernelGGL((score_kernel<ushort, HH * HIDD, 1>), dim3(NN / 4), dim3(256), 0, stream,
                       cat2b, vbuf + 5120, f1, f2);
    hipLaunchKernelGGL(gmax_kernel, dim3(1), dim3(256), 0, stream, f2, gm);
    hipLaunchKernelGGL((agg_mfma_kernel<OUTD, 0, 4>), dim3(NN / 16, 1, 1), dim3(256), 0, stream,
                       hT, f1, f2, gm, mb, (const float*)nullptr, h3, OUTD);

    hipLaunchKernelGGL(final_kernel, dim3(NN / 256), dim3(256), 0, stream, h3, out);
}